// Round 1
// 253.041 us; speedup vs baseline: 1.0890x; 1.0890x over previous
//
#include <hip/hip_runtime.h>

#define N_NODES 100000
#define DIM 256
#define KC 16
#define NE 3200000
#define CHUNK 64
#define NCHUNKS ((N_NODES + CHUNK - 1) / CHUNK)   // 1563 (last chunk = 32 nodes)

using bf16x8 = __attribute__((ext_vector_type(8))) short;
using f32x4  = __attribute__((ext_vector_type(4))) float;

__device__ __forceinline__ float bflo(unsigned u) { return __uint_as_float(u << 16); }
__device__ __forceinline__ unsigned short f2bf(float f) {  // RNE
    unsigned u = __float_as_uint(f);
    return (unsigned short)((u + 0x7fffu + ((u >> 16) & 1u)) >> 16);
}
__device__ __forceinline__ unsigned packbf(float a, float b) {
    return (unsigned)f2bf(a) | ((unsigned)f2bf(b) << 16);
}

// ---------------------------------------------------------------------------
// Fused assignment + S^T X, MFMA phase A. (unchanged except Sb pack: u8×255,
// 16 B/node instead of bf16 32 B/node — halves k_edges' divergent gathers.)
// ---------------------------------------------------------------------------
template <bool WRITE_PACK>
__global__ __launch_bounds__(256) void k_assign_stx(const float4* __restrict__ X4,
                                                    const float4* __restrict__ W4,
                                                    const float* __restrict__ bias,
                                                    float* __restrict__ S,
                                                    unsigned* __restrict__ Sb,
                                                    float* __restrict__ cs_g,
                                                    float* __restrict__ stx) {
    __shared__ unsigned short Xbf[CHUNK * 264];   // 33.8 KB, row stride 264 bf16
    __shared__ float ps[CHUNK * 20];              // p[node][16], stride 20 (f4-aligned)
    __shared__ float csred[4][KC];

    const int lane = threadIdx.x & 63;
    const int wv   = threadIdx.x >> 6;
    const int col  = lane & 15;          // MFMA col (cluster) / A-frag row
    const int quad = lane >> 4;
    const int d    = threadIdx.x;        // phase-B column

    // ---- W -> 8 register B-frags (once per block)
    bf16x8 wfrag[8];
    #pragma unroll
    for (int s = 0; s < 8; s++) {
        float4 wa = W4[col * 64 + s * 8 + quad * 2];
        float4 wb = W4[col * 64 + s * 8 + quad * 2 + 1];
        union { bf16x8 v; unsigned u[4]; } wf;
        wf.u[0] = packbf(wa.x, wa.y);
        wf.u[1] = packbf(wa.z, wa.w);
        wf.u[2] = packbf(wb.x, wb.y);
        wf.u[3] = packbf(wb.z, wb.w);
        wfrag[s] = wf.v;
    }
    const float bk = bias[col];

    float st[KC];
    #pragma unroll
    for (int k = 0; k < KC; k++) st[k] = 0.f;
    float csacc = 0.f;

    for (int ch = blockIdx.x; ch < NCHUNKS; ch += gridDim.x) {
        const int base = ch * CHUNK;
        __syncthreads();   // Xbf/ps free (previous phase B done)

        // ---- stage X chunk as bf16 (coalesced: 64 lanes x consecutive f4)
        {
            const int c4 = threadIdx.x & 63;
            const int r0 = threadIdx.x >> 6;
            #pragma unroll 4
            for (int s = 0; s < 16; s++) {
                int r = r0 + 4 * s;
                int rg = base + r;
                if (rg >= N_NODES) rg = N_NODES - 1;
                float4 x = X4[(size_t)rg * 64 + c4];
                *((uint2*)&Xbf[r * 264 + c4 * 4]) =
                    make_uint2(packbf(x.x, x.y), packbf(x.z, x.w));
            }
        }
        __syncthreads();

        // ---- phase A: 8 MFMAs -> logits for this wave's 16 nodes
        f32x4 acc = {0.f, 0.f, 0.f, 0.f};
        #pragma unroll
        for (int s = 0; s < 8; s++) {
            bf16x8 a = *(const bf16x8*)&Xbf[(wv * 16 + col) * 264 + s * 32 + quad * 8];
            acc = __builtin_amdgcn_mfma_f32_16x16x32_bf16(a, wfrag[s], acc, 0, 0, 0);
        }
        // softmax across cols (lanes 0-15 of each quad-group), per reg
        #pragma unroll
        for (int r = 0; r < 4; r++) {
            float lg = acc[r] + bk;
            float m = lg;
            #pragma unroll
            for (int off = 8; off >= 1; off >>= 1) m = fmaxf(m, __shfl_xor(m, off));
            float e = __expf(lg - m);
            float ssum = e;
            #pragma unroll
            for (int off = 8; off >= 1; off >>= 1) ssum += __shfl_xor(ssum, off);
            float pv = e / ssum;

            int nd = base + wv * 16 + quad * 4 + r;       // C-layout row -> node
            bool val = (nd < N_NODES);
            if (!val) pv = 0.f;
            if (val) S[(size_t)nd * KC + col] = pv;       // 16 lanes -> 64 B
            ps[(wv * 16 + quad * 4 + r) * 20 + col] = pv; // conflict-free
            csacc += pv;
            if (WRITE_PACK) {
                // u8 quantize (×255, RNE) and gather 4 cols/dword via shfl.
                // node is uniform across the 16-lane col group, so xor-1/xor-2
                // mix cols of the SAME node.
                unsigned qb = __float2uint_rn(pv * 255.f);
                unsigned p01 = qb | (((unsigned)__shfl_xor((int)qb, 1)) << 8);
                unsigned p0123 = p01 | (((unsigned)__shfl_xor((int)p01, 2)) << 16);
                if (val && !(col & 3))
                    Sb[(size_t)nd * 4 + (col >> 2)] = p0123;  // dword j = cols 4j..4j+3
            }
        }
        __syncthreads();

        // ---- phase B: st[k] += p[i][k] * X[i][d]
        #pragma unroll 4
        for (int i = 0; i < CHUNK; i++) {
            float x = bflo((unsigned)Xbf[i * 264 + d]);   // 2-way alias: free
            const float4* pp = (const float4*)&ps[i * 20];
            float4 p0 = pp[0], p1 = pp[1], p2 = pp[2], p3 = pp[3];
            st[0]  += p0.x * x; st[1]  += p0.y * x; st[2]  += p0.z * x; st[3]  += p0.w * x;
            st[4]  += p1.x * x; st[5]  += p1.y * x; st[6]  += p1.z * x; st[7]  += p1.w * x;
            st[8]  += p2.x * x; st[9]  += p2.y * x; st[10] += p2.z * x; st[11] += p2.w * x;
            st[12] += p3.x * x; st[13] += p3.y * x; st[14] += p3.z * x; st[15] += p3.w * x;
        }
    }

    // ---- epilogues
    #pragma unroll
    for (int k = 0; k < KC; k++) atomicAdd(&stx[k * DIM + d], st[k]);

    csacc += __shfl_xor(csacc, 16);
    csacc += __shfl_xor(csacc, 32);
    if (lane < KC) csred[wv][col] = csacc;
    __syncthreads();
    if (threadIdx.x < KC) {
        int t = threadIdx.x;
        atomicAdd(&cs_g[t], csred[0][t] + csred[1][t] + csred[2][t] + csred[3][t]);
    }
}

// ---------------------------------------------------------------------------
// Per-edge fused (u8-packed S): one uint4 gather per node (16 B, one 64 B line),
// 2 edges per iteration with int2/float2 streaming loads -> 4 independent
// divergent gathers in flight per thread-iteration.
// Accumulates in the ×255 scaled domain; unscaled once before reduction.
// ---------------------------------------------------------------------------
__device__ __forceinline__ void edge_acc_u8(uint4 qr, uint4 qc, float a,
                                            float (&lf)[KC], float& m2l, float& trl) {
    union { uint4 v; unsigned w[4]; } R, C;
    R.v = qr; C.v = qc;
    float dd = 0.f;
    #pragma unroll
    for (int q = 0; q < 4; q++) {
        unsigned x = R.w[q], y = C.w[q];
        float s0 = (float)(x & 0xffu);           // v_cvt_f32_ubyte0
        float s1 = (float)((x >> 8) & 0xffu);    // v_cvt_f32_ubyte1
        float s2 = (float)((x >> 16) & 0xffu);   // v_cvt_f32_ubyte2
        float s3 = (float)(x >> 24);             // v_cvt_f32_ubyte3
        float c0 = (float)(y & 0xffu);
        float c1 = (float)((y >> 8) & 0xffu);
        float c2 = (float)((y >> 16) & 0xffu);
        float c3 = (float)(y >> 24);
        dd = fmaf(s0, c0, dd); dd = fmaf(s1, c1, dd);
        dd = fmaf(s2, c2, dd); dd = fmaf(s3, c3, dd);
        lf[4 * q + 0] = fmaf(a, s0, lf[4 * q + 0]);
        lf[4 * q + 1] = fmaf(a, s1, lf[4 * q + 1]);
        lf[4 * q + 2] = fmaf(a, s2, lf[4 * q + 2]);
        lf[4 * q + 3] = fmaf(a, s3, lf[4 * q + 3]);
    }
    m2l += a;
    trl = fmaf(a, dd, trl);
}

__global__ __launch_bounds__(256) void k_edges_u8(const int* __restrict__ rows,
                                                  const int* __restrict__ cols,
                                                  const float* __restrict__ adj,
                                                  const uint4* __restrict__ Sb4,
                                                  float* __restrict__ m2_g,
                                                  float* __restrict__ tr_g,
                                                  float* __restrict__ left_g) {
    float m2l = 0.f, trl = 0.f;
    float lf[KC];
    #pragma unroll
    for (int k = 0; k < KC; k++) lf[k] = 0.f;

    const int NU = NE / 2;                        // 1.6M 2-edge units
    const int stride = gridDim.x * blockDim.x;
    for (int u = blockIdx.x * blockDim.x + threadIdx.x; u < NU; u += stride) {
        int2   r2 = *(const int2*)(rows + 2 * (size_t)u);
        int2   c2 = *(const int2*)(cols + 2 * (size_t)u);
        float2 a2 = *(const float2*)(adj + 2 * (size_t)u);
        uint4 qr0 = Sb4[r2.x];                    // 4 independent 16 B gathers
        uint4 qc0 = Sb4[c2.x];
        uint4 qr1 = Sb4[r2.y];
        uint4 qc1 = Sb4[c2.y];
        edge_acc_u8(qr0, qc0, a2.x, lf, m2l, trl);
        edge_acc_u8(qr1, qc1, a2.y, lf, m2l, trl);
    }

    trl *= (1.f / 65025.f);                       // undo 255^2 scale
    #pragma unroll
    for (int k = 0; k < KC; k++) lf[k] *= (1.f / 255.f);

    #pragma unroll
    for (int off = 32; off >= 1; off >>= 1) {
        m2l += __shfl_xor(m2l, off);
        trl += __shfl_xor(trl, off);
    }
    #pragma unroll
    for (int k = 0; k < KC; k++) {
        float v = lf[k];
        #pragma unroll
        for (int off = 32; off >= 1; off >>= 1) v += __shfl_xor(v, off);
        lf[k] = v;
    }
    __shared__ float red[4][18];
    int w = threadIdx.x >> 6;
    if ((threadIdx.x & 63) == 0) {
        red[w][0] = m2l; red[w][1] = trl;
        #pragma unroll
        for (int k = 0; k < KC; k++) red[w][2 + k] = lf[k];
    }
    __syncthreads();
    int t = threadIdx.x;
    if (t < 18) {
        float v = red[0][t] + red[1][t] + red[2][t] + red[3][t];
        float* dst = (t == 0) ? m2_g : (t == 1) ? tr_g : &left_g[t - 2];
        atomicAdd(dst, v);
    }
}

// ---------------------------------------------------------------------------
// f32 fallback edge kernel (workspace too small for Sb)
// ---------------------------------------------------------------------------
__global__ __launch_bounds__(256) void k_edges_f32(const int* __restrict__ rows,
                                                   const int* __restrict__ cols,
                                                   const float* __restrict__ adj,
                                                   const float* __restrict__ S,
                                                   float* __restrict__ m2_g,
                                                   float* __restrict__ tr_g,
                                                   float* __restrict__ left_g) {
    float m2l = 0.f, trl = 0.f;
    float lf[KC];
    #pragma unroll
    for (int k = 0; k < KC; k++) lf[k] = 0.f;

    int stride = gridDim.x * blockDim.x;
    for (int e = blockIdx.x * blockDim.x + threadIdx.x; e < NE; e += stride) {
        int r = rows[e], c = cols[e];
        float a = adj[e];
        float sv[KC], cv[KC];
        const float4* sr = (const float4*)(S + (size_t)r * KC);
        const float4* sc = (const float4*)(S + (size_t)c * KC);
        #pragma unroll
        for (int qq = 0; qq < 4; qq++) {
            float4 s4 = sr[qq], c4 = sc[qq];
            sv[4*qq]=s4.x; sv[4*qq+1]=s4.y; sv[4*qq+2]=s4.z; sv[4*qq+3]=s4.w;
            cv[4*qq]=c4.x; cv[4*qq+1]=c4.y; cv[4*qq+2]=c4.z; cv[4*qq+3]=c4.w;
        }
        float dd = 0.f;
        #pragma unroll
        for (int k = 0; k < KC; k++) {
            dd += sv[k] * cv[k];
            lf[k] += a * sv[k];
        }
        m2l += a;
        trl += a * dd;
    }

    #pragma unroll
    for (int off = 32; off >= 1; off >>= 1) {
        m2l += __shfl_xor(m2l, off);
        trl += __shfl_xor(trl, off);
    }
    #pragma unroll
    for (int k = 0; k < KC; k++) {
        float v = lf[k];
        #pragma unroll
        for (int off = 32; off >= 1; off >>= 1) v += __shfl_xor(v, off);
        lf[k] = v;
    }
    __shared__ float red[4][18];
    int w = threadIdx.x >> 6;
    if ((threadIdx.x & 63) == 0) {
        red[w][0] = m2l; red[w][1] = trl;
        #pragma unroll
        for (int k = 0; k < KC; k++) red[w][2 + k] = lf[k];
    }
    __syncthreads();
    int t = threadIdx.x;
    if (t < 18) {
        float v = red[0][t] + red[1][t] + red[2][t] + red[3][t];
        float* dst = (t == 0) ? m2_g : (t == 1) ? tr_g : &left_g[t - 2];
        atomicAdd(dst, v);
    }
}

// ---------------------------------------------------------------------------
// epilogue: features_pooled = selu(stx/cs), spectral & collapse losses (f32)
// ---------------------------------------------------------------------------
__global__ __launch_bounds__(256) void k_final(const float* __restrict__ cs,
                                               const float* __restrict__ left,
                                               const float* __restrict__ m2p,
                                               const float* __restrict__ trp,
                                               const float* __restrict__ stx,
                                               float* __restrict__ out) {
    int t = threadIdx.x;
    #pragma unroll
    for (int k = 0; k < KC; k++) {
        float v = stx[k * DIM + t] / cs[k];
        float r = (v > 0.f) ? 1.0507009873554805f * v
                            : 1.7580993408473766f * (__expf(v) - 1.f);
        out[k * DIM + t] = r;
    }
    if (t == 0) {
        float m2 = *m2p;
        float tn = 0.f;
        #pragma unroll
        for (int k = 0; k < KC; k++) tn += left[k] * left[k];
        tn /= m2;
        float spectral = -((*trp) - tn) / m2;
        float ss = 0.f;
        #pragma unroll
        for (int k = 0; k < KC; k++) ss += cs[k] * cs[k];
        float collapse = 0.1f * (sqrtf(ss) / (float)N_NODES * 4.0f - 1.0f);
        out[KC * DIM + (size_t)N_NODES * KC]     = spectral;
        out[KC * DIM + (size_t)N_NODES * KC + 1] = collapse;
    }
}

extern "C" void kernel_launch(void* const* d_in, const int* in_sizes, int n_in,
                              void* d_out, int out_size, void* d_ws, size_t ws_size,
                              hipStream_t stream) {
    (void)out_size;

    const float* X    = nullptr;
    const int*   ei   = nullptr;
    const float* adj  = nullptr;
    const float* W    = nullptr;
    const float* bias = nullptr;
    for (int i = 0; i < n_in; i++) {
        switch (in_sizes[i]) {
            case 25600000: X    = (const float*)d_in[i]; break;
            case  6400000: ei   = (const int*)d_in[i];   break;
            case  3200000: adj  = (const float*)d_in[i]; break;
            case     4096: W    = (const float*)d_in[i]; break;
            case       16: bias = (const float*)d_in[i]; break;
        }
    }

    float* out = (float*)d_out;
    float* S   = out + KC * DIM;    // assignments [100000,16] f32
    const int* rows = ei;
    const int* cols = ei + NE;

    float* ws   = (float*)d_ws;
    float* cs   = ws;
    float* left = ws + 16;
    float* m2   = ws + 32;
    float* tr   = ws + 33;
    float* stx  = ws + 64;
    unsigned* Sb = (unsigned*)(ws + 64 + KC * DIM);   // u8-packed S, 16 B/node
    const size_t need = (64 + KC * DIM) * sizeof(float) + (size_t)N_NODES * 16;
    const bool use_pack = (ws_size >= need);   // fixed per process -> graph-safe

    hipMemsetAsync(d_ws, 0, (64 + KC * DIM) * sizeof(float), stream);

    const int agrid = 782;   // 2 chunks/block over 1563 chunks, ~3 blocks/CU
    if (use_pack) {
        k_assign_stx<true><<<agrid, 256, 0, stream>>>(
            (const float4*)X, (const float4*)W, bias, S, Sb, cs, stx);
        k_edges_u8<<<2048, 256, 0, stream>>>(rows, cols, adj, (const uint4*)Sb,
                                             m2, tr, left);
    } else {
        k_assign_stx<false><<<agrid, 256, 0, stream>>>(
            (const float4*)X, (const float4*)W, bias, S, Sb, cs, stx);
        k_edges_f32<<<2048, 256, 0, stream>>>(rows, cols, adj, S, m2, tr, left);
    }
    k_final<<<1, 256, 0, stream>>>(cs, left, m2, tr, stx, out);
}

// Round 3
// 248.741 us; speedup vs baseline: 1.1078x; 1.0173x over previous
//
#include <hip/hip_runtime.h>

#define N_NODES 100000
#define DIM 256
#define KC 16
#define NE 3200000
#define CHUNK 64
#define NCHUNKS ((N_NODES + CHUNK - 1) / CHUNK)   // 1563 (last chunk = 32 nodes)

// LDS layout strides (u16 units)
#define D0STR 1168   // per 16-dim block: 8 groups * 144 + 16 pad  (2336 B)
#define GSTR  144    // per 8-node group: 8*16 + 16 pad            (288 B)
#define PSTR  72     // P' row stride (64 nodes + 8 pad)           (144 B)
#define PLANE (16 * PSTR)

using bf16x8 = __attribute__((ext_vector_type(8))) short;
using f32x4  = __attribute__((ext_vector_type(4))) float;

__device__ __forceinline__ unsigned short f2bf(float f) {  // RNE
    unsigned u = __float_as_uint(f);
    return (unsigned short)((u + 0x7fffu + ((u >> 16) & 1u)) >> 16);
}
__device__ __forceinline__ unsigned packbf(float a, float b) {
    return (unsigned)f2bf(a) | ((unsigned)f2bf(b) << 16);
}

// ---------------------------------------------------------------------------
// Fused assignment + S^T X, both phases MFMA.
//  stage:   X chunk -> LDS bf16, 16-dim-subtiled: elem (node,dim) at u16
//           offset (dim>>4)*D0STR + (node>>3)*GSTR + (node&7)*16 + (dim&15).
//  phase A: logits^T = W·X^T via mfma(wfrag, xfrag); lane (c,quad) reg r
//           holds logits[cluster=quad*4+r][node=wv*16+c]. Softmax = 3 VALU
//           max + 2 shfl. Writes S (one float4/lane), Sb (one u32/lane),
//           P' transposed to LDS as bf16 hi+residual planes (f32-grade).
//  phase B: st[16][256] += P'·X per chunk. A-frags = psb b128 reads
//           (cluster-major, verified layout). B-frags = 8 ds_read_u16
//           node-gathers per MFMA pair from Xs (conflict-free: bank =
//           8*quad + c/2 covers all 32 banks 2-way). 16 MFMAs/wave/chunk.
//           NO ds_read_b64_tr_b16 (round-2 failure isolated to it).
// ---------------------------------------------------------------------------
template <bool WRITE_PACK>
__global__ __launch_bounds__(256) void k_assign_stx(const float4* __restrict__ X4,
                                                    const float4* __restrict__ W4,
                                                    const float* __restrict__ bias,
                                                    float* __restrict__ S,
                                                    unsigned* __restrict__ Sb,
                                                    float* __restrict__ cs_g,
                                                    float* __restrict__ stx) {
    __shared__ __align__(16) unsigned short Xs[16 * D0STR];       // 37.4 KB
    __shared__ __align__(16) unsigned short psb[2 * 16 * PSTR];   // 4.6 KB
    __shared__ float csred[4][KC];

    const int lane = threadIdx.x & 63;
    const int wv   = threadIdx.x >> 6;
    const int c    = lane & 15;
    const int quad = lane >> 4;

    // ---- W -> 8 register frags (A-operand layout: row=lane&15, k=quad*8+j)
    bf16x8 wfrag[8];
    #pragma unroll
    for (int s = 0; s < 8; s++) {
        float4 wa = W4[c * 64 + s * 8 + quad * 2];
        float4 wb = W4[c * 64 + s * 8 + quad * 2 + 1];
        union { bf16x8 v; unsigned u[4]; } wf;
        wf.u[0] = packbf(wa.x, wa.y);
        wf.u[1] = packbf(wa.z, wa.w);
        wf.u[2] = packbf(wb.x, wb.y);
        wf.u[3] = packbf(wb.z, wb.w);
        wfrag[s] = wf.v;
    }
    const float4 b4 = ((const float4*)bias)[quad];   // bias[quad*4 .. +3]

    f32x4 acc[4];
    #pragma unroll
    for (int t = 0; t < 4; t++) acc[t] = (f32x4){0.f, 0.f, 0.f, 0.f};
    float csr[4] = {0.f, 0.f, 0.f, 0.f};

    for (int ch = blockIdx.x; ch < NCHUNKS; ch += gridDim.x) {
        const int base = ch * CHUNK;
        __syncthreads();   // Xs/psb free (previous phase B done)

        // ---- stage X chunk (coalesced f4 loads -> subtiled bf16 writes)
        {
            const int c4  = threadIdx.x & 63;
            const int r0  = threadIdx.x >> 6;
            const int d0s = c4 >> 2;
            const int wo  = (c4 & 3) * 4;
            #pragma unroll 4
            for (int s = 0; s < 16; s++) {
                int r = r0 + 4 * s;
                int rg = base + r;
                if (rg >= N_NODES) rg = N_NODES - 1;
                float4 x = X4[(size_t)rg * 64 + c4];
                *(uint2*)&Xs[d0s * D0STR + (r >> 3) * GSTR + (r & 7) * 16 + wo] =
                    make_uint2(packbf(x.x, x.y), packbf(x.z, x.w));
            }
        }
        __syncthreads();

        // ---- phase A: logits^T (D[m=cluster][n=node]); B-frag = node's dims
        f32x4 la = {0.f, 0.f, 0.f, 0.f};
        {
            const int node = wv * 16 + c;
            const int gA = node >> 3, n8 = node & 7;
            #pragma unroll
            for (int s = 0; s < 8; s++) {
                const int d0 = 2 * s + (quad >> 1);
                bf16x8 xf = *(const bf16x8*)&Xs[d0 * D0STR + gA * GSTR + n8 * 16 + (quad & 1) * 8];
                la = __builtin_amdgcn_mfma_f32_16x16x32_bf16(wfrag[s], xf, la, 0, 0, 0);
            }
        }
        // softmax over clusters (4 regs x 4 quads)
        float lg0 = la[0] + b4.x, lg1 = la[1] + b4.y;
        float lg2 = la[2] + b4.z, lg3 = la[3] + b4.w;
        float mx = fmaxf(fmaxf(lg0, lg1), fmaxf(lg2, lg3));
        mx = fmaxf(mx, __shfl_xor(mx, 16));
        mx = fmaxf(mx, __shfl_xor(mx, 32));
        float e0 = __expf(lg0 - mx), e1 = __expf(lg1 - mx);
        float e2 = __expf(lg2 - mx), e3 = __expf(lg3 - mx);
        float ssum = e0 + e1 + e2 + e3;
        ssum += __shfl_xor(ssum, 16);
        ssum += __shfl_xor(ssum, 32);
        float inv = 1.f / ssum;
        float pvv[4] = {e0 * inv, e1 * inv, e2 * inv, e3 * inv};

        const int nn = wv * 16 + c;
        const int nd = base + nn;
        if (nd >= N_NODES) {
            pvv[0] = pvv[1] = pvv[2] = pvv[3] = 0.f;
        } else {
            *(float4*)&S[(size_t)nd * KC + quad * 4] =
                make_float4(pvv[0], pvv[1], pvv[2], pvv[3]);
            if (WRITE_PACK) {
                unsigned q0 = __float2uint_rn(pvv[0] * 255.f);
                unsigned q1 = __float2uint_rn(pvv[1] * 255.f);
                unsigned q2 = __float2uint_rn(pvv[2] * 255.f);
                unsigned q3 = __float2uint_rn(pvv[3] * 255.f);
                Sb[(size_t)nd * 4 + quad] = q0 | (q1 << 8) | (q2 << 16) | (q3 << 24);
            }
        }
        // P' transposed hi+residual bf16 planes; cluster-size accumulation
        #pragma unroll
        for (int r = 0; r < 4; r++) {
            unsigned short ph = f2bf(pvv[r]);
            float pl = pvv[r] - __uint_as_float(((unsigned)ph) << 16);
            psb[(quad * 4 + r) * PSTR + nn] = ph;
            psb[PLANE + (quad * 4 + r) * PSTR + nn] = f2bf(pl);
            csr[r] += pvv[r];
        }
        __syncthreads();   // psb ready

        // ---- phase B: acc += P' · X  (M=cluster, N=dim-tile, K=64 nodes)
        bf16x8 afH[2], afL[2];
        #pragma unroll
        for (int ks = 0; ks < 2; ks++) {
            afH[ks] = *(const bf16x8*)&psb[c * PSTR + ks * 32 + quad * 8];
            afL[ks] = *(const bf16x8*)&psb[PLANE + c * PSTR + ks * 32 + quad * 8];
        }
        #pragma unroll
        for (int t = 0; t < 4; t++) {
            const int d0  = wv * 4 + t;
            const int dlo = c;                       // dim = d0*16 + c
            union { bf16x8 v; unsigned short h[8]; } bf0, bf1;
            #pragma unroll
            for (int j = 0; j < 8; j++) {
                const int n0 = quad * 8 + j;         // ks=0: nodes 0..31
                bf0.h[j] = Xs[d0 * D0STR + (n0 >> 3) * GSTR + (n0 & 7) * 16 + dlo];
                const int n1 = 32 + n0;              // ks=1: nodes 32..63
                bf1.h[j] = Xs[d0 * D0STR + (n1 >> 3) * GSTR + (n1 & 7) * 16 + dlo];
            }
            acc[t] = __builtin_amdgcn_mfma_f32_16x16x32_bf16(afH[0], bf0.v, acc[t], 0, 0, 0);
            acc[t] = __builtin_amdgcn_mfma_f32_16x16x32_bf16(afL[0], bf0.v, acc[t], 0, 0, 0);
            acc[t] = __builtin_amdgcn_mfma_f32_16x16x32_bf16(afH[1], bf1.v, acc[t], 0, 0, 0);
            acc[t] = __builtin_amdgcn_mfma_f32_16x16x32_bf16(afL[1], bf1.v, acc[t], 0, 0, 0);
        }
    }

    // ---- epilogue: one atomic pass for st; cluster sizes
    #pragma unroll
    for (int t = 0; t < 4; t++) {
        #pragma unroll
        for (int r = 0; r < 4; r++)
            atomicAdd(&stx[(quad * 4 + r) * DIM + (wv * 4 + t) * 16 + c], acc[t][r]);
    }

    #pragma unroll
    for (int r = 0; r < 4; r++) {
        float v = csr[r];
        v += __shfl_xor(v, 1); v += __shfl_xor(v, 2);
        v += __shfl_xor(v, 4); v += __shfl_xor(v, 8);
        csr[r] = v;
    }
    if (c == 0) {
        #pragma unroll
        for (int r = 0; r < 4; r++) csred[wv][quad * 4 + r] = csr[r];
    }
    __syncthreads();
    if (threadIdx.x < KC) {
        int t = threadIdx.x;
        atomicAdd(&cs_g[t], csred[0][t] + csred[1][t] + csred[2][t] + csred[3][t]);
    }
}

// ---------------------------------------------------------------------------
// Per-edge fused (u8-packed S): one uint4 gather per node, 2 edges/iter.
// ---------------------------------------------------------------------------
__device__ __forceinline__ void edge_acc_u8(uint4 qr, uint4 qc, float a,
                                            float (&lf)[KC], float& m2l, float& trl) {
    union { uint4 v; unsigned w[4]; } R, C;
    R.v = qr; C.v = qc;
    float dd = 0.f;
    #pragma unroll
    for (int q = 0; q < 4; q++) {
        unsigned x = R.w[q], y = C.w[q];
        float s0 = (float)(x & 0xffu);
        float s1 = (float)((x >> 8) & 0xffu);
        float s2 = (float)((x >> 16) & 0xffu);
        float s3 = (float)(x >> 24);
        float c0 = (float)(y & 0xffu);
        float c1 = (float)((y >> 8) & 0xffu);
        float c2 = (float)((y >> 16) & 0xffu);
        float c3 = (float)(y >> 24);
        dd = fmaf(s0, c0, dd); dd = fmaf(s1, c1, dd);
        dd = fmaf(s2, c2, dd); dd = fmaf(s3, c3, dd);
        lf[4 * q + 0] = fmaf(a, s0, lf[4 * q + 0]);
        lf[4 * q + 1] = fmaf(a, s1, lf[4 * q + 1]);
        lf[4 * q + 2] = fmaf(a, s2, lf[4 * q + 2]);
        lf[4 * q + 3] = fmaf(a, s3, lf[4 * q + 3]);
    }
    m2l += a;
    trl = fmaf(a, dd, trl);
}

__global__ __launch_bounds__(256) void k_edges_u8(const int* __restrict__ rows,
                                                  const int* __restrict__ cols,
                                                  const float* __restrict__ adj,
                                                  const uint4* __restrict__ Sb4,
                                                  float* __restrict__ m2_g,
                                                  float* __restrict__ tr_g,
                                                  float* __restrict__ left_g) {
    float m2l = 0.f, trl = 0.f;
    float lf[KC];
    #pragma unroll
    for (int k = 0; k < KC; k++) lf[k] = 0.f;

    const int NU = NE / 2;
    const int stride = gridDim.x * blockDim.x;
    for (int u = blockIdx.x * blockDim.x + threadIdx.x; u < NU; u += stride) {
        int2   r2 = *(const int2*)(rows + 2 * (size_t)u);
        int2   c2 = *(const int2*)(cols + 2 * (size_t)u);
        float2 a2 = *(const float2*)(adj + 2 * (size_t)u);
        uint4 qr0 = Sb4[r2.x];
        uint4 qc0 = Sb4[c2.x];
        uint4 qr1 = Sb4[r2.y];
        uint4 qc1 = Sb4[c2.y];
        edge_acc_u8(qr0, qc0, a2.x, lf, m2l, trl);
        edge_acc_u8(qr1, qc1, a2.y, lf, m2l, trl);
    }

    trl *= (1.f / 65025.f);
    #pragma unroll
    for (int k = 0; k < KC; k++) lf[k] *= (1.f / 255.f);

    #pragma unroll
    for (int off = 32; off >= 1; off >>= 1) {
        m2l += __shfl_xor(m2l, off);
        trl += __shfl_xor(trl, off);
    }
    #pragma unroll
    for (int k = 0; k < KC; k++) {
        float v = lf[k];
        #pragma unroll
        for (int off = 32; off >= 1; off >>= 1) v += __shfl_xor(v, off);
        lf[k] = v;
    }
    __shared__ float red[4][18];
    int w = threadIdx.x >> 6;
    if ((threadIdx.x & 63) == 0) {
        red[w][0] = m2l; red[w][1] = trl;
        #pragma unroll
        for (int k = 0; k < KC; k++) red[w][2 + k] = lf[k];
    }
    __syncthreads();
    int t = threadIdx.x;
    if (t < 18) {
        float v = red[0][t] + red[1][t] + red[2][t] + red[3][t];
        float* dst = (t == 0) ? m2_g : (t == 1) ? tr_g : &left_g[t - 2];
        atomicAdd(dst, v);
    }
}

// ---------------------------------------------------------------------------
// f32 fallback edge kernel (workspace too small for Sb)
// ---------------------------------------------------------------------------
__global__ __launch_bounds__(256) void k_edges_f32(const int* __restrict__ rows,
                                                   const int* __restrict__ cols,
                                                   const float* __restrict__ adj,
                                                   const float* __restrict__ S,
                                                   float* __restrict__ m2_g,
                                                   float* __restrict__ tr_g,
                                                   float* __restrict__ left_g) {
    float m2l = 0.f, trl = 0.f;
    float lf[KC];
    #pragma unroll
    for (int k = 0; k < KC; k++) lf[k] = 0.f;

    int stride = gridDim.x * blockDim.x;
    for (int e = blockIdx.x * blockDim.x + threadIdx.x; e < NE; e += stride) {
        int r = rows[e], c = cols[e];
        float a = adj[e];
        float sv[KC], cv[KC];
        const float4* sr = (const float4*)(S + (size_t)r * KC);
        const float4* sc = (const float4*)(S + (size_t)c * KC);
        #pragma unroll
        for (int qq = 0; qq < 4; qq++) {
            float4 s4 = sr[qq], c4 = sc[qq];
            sv[4*qq]=s4.x; sv[4*qq+1]=s4.y; sv[4*qq+2]=s4.z; sv[4*qq+3]=s4.w;
            cv[4*qq]=c4.x; cv[4*qq+1]=c4.y; cv[4*qq+2]=c4.z; cv[4*qq+3]=c4.w;
        }
        float dd = 0.f;
        #pragma unroll
        for (int k = 0; k < KC; k++) {
            dd += sv[k] * cv[k];
            lf[k] += a * sv[k];
        }
        m2l += a;
        trl += a * dd;
    }

    #pragma unroll
    for (int off = 32; off >= 1; off >>= 1) {
        m2l += __shfl_xor(m2l, off);
        trl += __shfl_xor(trl, off);
    }
    #pragma unroll
    for (int k = 0; k < KC; k++) {
        float v = lf[k];
        #pragma unroll
        for (int off = 32; off >= 1; off >>= 1) v += __shfl_xor(v, off);
        lf[k] = v;
    }
    __shared__ float red[4][18];
    int w = threadIdx.x >> 6;
    if ((threadIdx.x & 63) == 0) {
        red[w][0] = m2l; red[w][1] = trl;
        #pragma unroll
        for (int k = 0; k < KC; k++) red[w][2 + k] = lf[k];
    }
    __syncthreads();
    int t = threadIdx.x;
    if (t < 18) {
        float v = red[0][t] + red[1][t] + red[2][t] + red[3][t];
        float* dst = (t == 0) ? m2_g : (t == 1) ? tr_g : &left_g[t - 2];
        atomicAdd(dst, v);
    }
}

// ---------------------------------------------------------------------------
// epilogue: features_pooled = selu(stx/cs), spectral & collapse losses (f32)
// ---------------------------------------------------------------------------
__global__ __launch_bounds__(256) void k_final(const float* __restrict__ cs,
                                               const float* __restrict__ left,
                                               const float* __restrict__ m2p,
                                               const float* __restrict__ trp,
                                               const float* __restrict__ stx,
                                               float* __restrict__ out) {
    int t = threadIdx.x;
    #pragma unroll
    for (int k = 0; k < KC; k++) {
        float v = stx[k * DIM + t] / cs[k];
        float r = (v > 0.f) ? 1.0507009873554805f * v
                            : 1.7580993408473766f * (__expf(v) - 1.f);
        out[k * DIM + t] = r;
    }
    if (t == 0) {
        float m2 = *m2p;
        float tn = 0.f;
        #pragma unroll
        for (int k = 0; k < KC; k++) tn += left[k] * left[k];
        tn /= m2;
        float spectral = -((*trp) - tn) / m2;
        float ss = 0.f;
        #pragma unroll
        for (int k = 0; k < KC; k++) ss += cs[k] * cs[k];
        float collapse = 0.1f * (sqrtf(ss) / (float)N_NODES * 4.0f - 1.0f);
        out[KC * DIM + (size_t)N_NODES * KC]     = spectral;
        out[KC * DIM + (size_t)N_NODES * KC + 1] = collapse;
    }
}

extern "C" void kernel_launch(void* const* d_in, const int* in_sizes, int n_in,
                              void* d_out, int out_size, void* d_ws, size_t ws_size,
                              hipStream_t stream) {
    (void)out_size;

    const float* X    = nullptr;
    const int*   ei   = nullptr;
    const float* adj  = nullptr;
    const float* W    = nullptr;
    const float* bias = nullptr;
    for (int i = 0; i < n_in; i++) {
        switch (in_sizes[i]) {
            case 25600000: X    = (const float*)d_in[i]; break;
            case  6400000: ei   = (const int*)d_in[i];   break;
            case  3200000: adj  = (const float*)d_in[i]; break;
            case     4096: W    = (const float*)d_in[i]; break;
            case       16: bias = (const float*)d_in[i]; break;
        }
    }

    float* out = (float*)d_out;
    float* S   = out + KC * DIM;    // assignments [100000,16] f32
    const int* rows = ei;
    const int* cols = ei + NE;

    float* ws   = (float*)d_ws;
    float* cs   = ws;
    float* left = ws + 16;
    float* m2   = ws + 32;
    float* tr   = ws + 33;
    float* stx  = ws + 64;
    unsigned* Sb = (unsigned*)(ws + 64 + KC * DIM);   // u8-packed S, 16 B/node
    const size_t need = (64 + KC * DIM) * sizeof(float) + (size_t)N_NODES * 16;
    const bool use_pack = (ws_size >= need);   // fixed per process -> graph-safe

    hipMemsetAsync(d_ws, 0, (64 + KC * DIM) * sizeof(float), stream);

    const int agrid = 782;   // 2 chunks/block over 1563 chunks, ~3 blocks/CU
    if (use_pack) {
        k_assign_stx<true><<<agrid, 256, 0, stream>>>(
            (const float4*)X, (const float4*)W, bias, S, Sb, cs, stx);
        k_edges_u8<<<2048, 256, 0, stream>>>(rows, cols, adj, (const uint4*)Sb,
                                             m2, tr, left);
    } else {
        k_assign_stx<false><<<agrid, 256, 0, stream>>>(
            (const float4*)X, (const float4*)W, bias, S, Sb, cs, stx);
        k_edges_f32<<<2048, 256, 0, stream>>>(rows, cols, adj, S, m2, tr, left);
    }
    k_final<<<1, 256, 0, stream>>>(cs, left, m2, tr, stx, out);
}

// Round 4
// 247.970 us; speedup vs baseline: 1.1113x; 1.0031x over previous
//
#include <hip/hip_runtime.h>

#define N_NODES 100000
#define DIM 256
#define KC 16
#define NE 3200000
#define CHUNK 64
#define NCHUNKS ((N_NODES + CHUNK - 1) / CHUNK)   // 1563 (last chunk = 32 nodes)

// LDS layout strides (u16 units)
#define D0STR 1168   // per 16-dim block: 8 groups * 144 + 16 pad  (2336 B)
#define GSTR  144    // per 8-node group: 8*16 + 16 pad            (288 B)
#define PSTR  72     // P' row stride (64 nodes + 8 pad)           (144 B)

using bf16x8 = __attribute__((ext_vector_type(8))) short;
using f32x4  = __attribute__((ext_vector_type(4))) float;

__device__ __forceinline__ unsigned short f2bf(float f) {  // RNE
    unsigned u = __float_as_uint(f);
    return (unsigned short)((u + 0x7fffu + ((u >> 16) & 1u)) >> 16);
}
__device__ __forceinline__ unsigned packbf(float a, float b) {
    return (unsigned)f2bf(a) | ((unsigned)f2bf(b) << 16);
}

// ---------------------------------------------------------------------------
// Fused assignment + S^T X, both phases MFMA. One chunk per block (grid 1563):
// removes intra-block chunk serialization; cross-block overlap hides latency.
//  stage:   reg-staged (2 batches of 8 outstanding dwordx4 loads -> MLP 8/wave)
//           then bf16 convert + subtiled LDS write. W frags interleaved.
//  phase A: logits^T = W·X^T, mfma(wfrag, xfrag). Unchanged from round 3.
//  phase B: st += P'·X, P' single bf16 plane (residual dropped: pooled error
//           ~1e-5 << threshold; saves 2.3 KB -> LDS 39936 B -> 4 blocks/CU).
// ---------------------------------------------------------------------------
template <bool WRITE_PACK>
__global__ __launch_bounds__(256, 4) void k_assign_stx(const float4* __restrict__ X4,
                                                       const float4* __restrict__ W4,
                                                       const float* __restrict__ bias,
                                                       float* __restrict__ S,
                                                       unsigned* __restrict__ Sb,
                                                       float* __restrict__ cs_g,
                                                       float* __restrict__ stx) {
    __shared__ __align__(16) unsigned short Xs[16 * D0STR];   // 37376 B
    __shared__ __align__(16) unsigned short psb[16 * PSTR];   // 2304 B
    __shared__ float csred[4][KC];                            // 256 B -> 39936 B total

    const int lane = threadIdx.x & 63;
    const int wv   = threadIdx.x >> 6;
    const int c    = lane & 15;
    const int quad = lane >> 4;

    const int base = blockIdx.x * CHUNK;

    // ---- staging geometry
    const int c4  = threadIdx.x & 63;
    const int r0  = threadIdx.x >> 6;
    const int d0s = c4 >> 2;
    const int wo  = (c4 & 3) * 4;

    // ---- batch 1: stage loads (8 outstanding), W loads interleaved
    float4 xr[8];
    #pragma unroll
    for (int s = 0; s < 8; s++) {
        int rg = base + r0 + 4 * s;
        if (rg >= N_NODES) rg = N_NODES - 1;
        xr[s] = X4[(size_t)rg * 64 + c4];
    }
    bf16x8 wfrag[8];
    #pragma unroll
    for (int s = 0; s < 4; s++) {
        float4 wa = W4[c * 64 + s * 8 + quad * 2];
        float4 wb = W4[c * 64 + s * 8 + quad * 2 + 1];
        union { bf16x8 v; unsigned u[4]; } wf;
        wf.u[0] = packbf(wa.x, wa.y);
        wf.u[1] = packbf(wa.z, wa.w);
        wf.u[2] = packbf(wb.x, wb.y);
        wf.u[3] = packbf(wb.z, wb.w);
        wfrag[s] = wf.v;
    }
    #pragma unroll
    for (int s = 0; s < 8; s++) {
        int r = r0 + 4 * s;
        *(uint2*)&Xs[d0s * D0STR + (r >> 3) * GSTR + (r & 7) * 16 + wo] =
            make_uint2(packbf(xr[s].x, xr[s].y), packbf(xr[s].z, xr[s].w));
    }
    // ---- batch 2
    #pragma unroll
    for (int s = 0; s < 8; s++) {
        int rg = base + r0 + 4 * (s + 8);
        if (rg >= N_NODES) rg = N_NODES - 1;
        xr[s] = X4[(size_t)rg * 64 + c4];
    }
    #pragma unroll
    for (int s = 4; s < 8; s++) {
        float4 wa = W4[c * 64 + s * 8 + quad * 2];
        float4 wb = W4[c * 64 + s * 8 + quad * 2 + 1];
        union { bf16x8 v; unsigned u[4]; } wf;
        wf.u[0] = packbf(wa.x, wa.y);
        wf.u[1] = packbf(wa.z, wa.w);
        wf.u[2] = packbf(wb.x, wb.y);
        wf.u[3] = packbf(wb.z, wb.w);
        wfrag[s] = wf.v;
    }
    #pragma unroll
    for (int s = 0; s < 8; s++) {
        int r = r0 + 4 * (s + 8);
        *(uint2*)&Xs[d0s * D0STR + (r >> 3) * GSTR + (r & 7) * 16 + wo] =
            make_uint2(packbf(xr[s].x, xr[s].y), packbf(xr[s].z, xr[s].w));
    }
    const float4 b4 = ((const float4*)bias)[quad];
    __syncthreads();

    // ---- phase A: logits^T (D[m=cluster][n=node]); B-frag = node's dims
    f32x4 la = {0.f, 0.f, 0.f, 0.f};
    {
        const int node = wv * 16 + c;
        const int gA = node >> 3, n8 = node & 7;
        #pragma unroll
        for (int s = 0; s < 8; s++) {
            const int d0 = 2 * s + (quad >> 1);
            bf16x8 xf = *(const bf16x8*)&Xs[d0 * D0STR + gA * GSTR + n8 * 16 + (quad & 1) * 8];
            la = __builtin_amdgcn_mfma_f32_16x16x32_bf16(wfrag[s], xf, la, 0, 0, 0);
        }
    }
    // softmax over clusters (4 regs x 4 quads)
    float lg0 = la[0] + b4.x, lg1 = la[1] + b4.y;
    float lg2 = la[2] + b4.z, lg3 = la[3] + b4.w;
    float mx = fmaxf(fmaxf(lg0, lg1), fmaxf(lg2, lg3));
    mx = fmaxf(mx, __shfl_xor(mx, 16));
    mx = fmaxf(mx, __shfl_xor(mx, 32));
    float e0 = __expf(lg0 - mx), e1 = __expf(lg1 - mx);
    float e2 = __expf(lg2 - mx), e3 = __expf(lg3 - mx);
    float ssum = e0 + e1 + e2 + e3;
    ssum += __shfl_xor(ssum, 16);
    ssum += __shfl_xor(ssum, 32);
    float inv = 1.f / ssum;
    float pvv[4] = {e0 * inv, e1 * inv, e2 * inv, e3 * inv};

    const int nn = wv * 16 + c;
    const int nd = base + nn;
    if (nd >= N_NODES) {
        pvv[0] = pvv[1] = pvv[2] = pvv[3] = 0.f;
    } else {
        *(float4*)&S[(size_t)nd * KC + quad * 4] =
            make_float4(pvv[0], pvv[1], pvv[2], pvv[3]);
        if (WRITE_PACK) {
            unsigned q0 = __float2uint_rn(pvv[0] * 255.f);
            unsigned q1 = __float2uint_rn(pvv[1] * 255.f);
            unsigned q2 = __float2uint_rn(pvv[2] * 255.f);
            unsigned q3 = __float2uint_rn(pvv[3] * 255.f);
            Sb[(size_t)nd * 4 + quad] = q0 | (q1 << 8) | (q2 << 16) | (q3 << 24);
        }
    }
    float csr[4];
    #pragma unroll
    for (int r = 0; r < 4; r++) {
        psb[(quad * 4 + r) * PSTR + nn] = f2bf(pvv[r]);
        csr[r] = pvv[r];
    }
    __syncthreads();   // psb + Xs ready for phase B

    // ---- phase B: acc += P' · X  (M=cluster, N=dim-tile, K=64 nodes)
    f32x4 acc[4];
    #pragma unroll
    for (int t = 0; t < 4; t++) acc[t] = (f32x4){0.f, 0.f, 0.f, 0.f};
    bf16x8 afH[2];
    afH[0] = *(const bf16x8*)&psb[c * PSTR + 0 * 32 + quad * 8];
    afH[1] = *(const bf16x8*)&psb[c * PSTR + 1 * 32 + quad * 8];
    #pragma unroll
    for (int t = 0; t < 4; t++) {
        const int d0  = wv * 4 + t;
        const int dlo = c;                       // dim = d0*16 + c
        union { bf16x8 v; unsigned short h[8]; } bf0, bf1;
        #pragma unroll
        for (int j = 0; j < 8; j++) {
            const int n0 = quad * 8 + j;         // ks=0: nodes 0..31
            bf0.h[j] = Xs[d0 * D0STR + (n0 >> 3) * GSTR + (n0 & 7) * 16 + dlo];
            const int n1 = 32 + n0;              // ks=1: nodes 32..63
            bf1.h[j] = Xs[d0 * D0STR + (n1 >> 3) * GSTR + (n1 & 7) * 16 + dlo];
        }
        acc[t] = __builtin_amdgcn_mfma_f32_16x16x32_bf16(afH[0], bf0.v, acc[t], 0, 0, 0);
        acc[t] = __builtin_amdgcn_mfma_f32_16x16x32_bf16(afH[1], bf1.v, acc[t], 0, 0, 0);
    }

    // ---- epilogue: one atomic pass for st; cluster sizes
    #pragma unroll
    for (int t = 0; t < 4; t++) {
        #pragma unroll
        for (int r = 0; r < 4; r++)
            atomicAdd(&stx[(quad * 4 + r) * DIM + (wv * 4 + t) * 16 + c], acc[t][r]);
    }

    #pragma unroll
    for (int r = 0; r < 4; r++) {
        float v = csr[r];
        v += __shfl_xor(v, 1); v += __shfl_xor(v, 2);
        v += __shfl_xor(v, 4); v += __shfl_xor(v, 8);
        csr[r] = v;
    }
    if (c == 0) {
        #pragma unroll
        for (int r = 0; r < 4; r++) csred[wv][quad * 4 + r] = csr[r];
    }
    __syncthreads();
    if (threadIdx.x < KC) {
        int t = threadIdx.x;
        atomicAdd(&cs_g[t], csred[0][t] + csred[1][t] + csred[2][t] + csred[3][t]);
    }
}

// ---------------------------------------------------------------------------
// Per-edge fused (u8-packed S): one uint4 gather per node, 4 edges/iter
// (8 independent gathers in flight -> 2x MLP vs round 3).
// ---------------------------------------------------------------------------
__device__ __forceinline__ void edge_acc_u8(uint4 qr, uint4 qc, float a,
                                            float (&lf)[KC], float& m2l, float& trl) {
    union { uint4 v; unsigned w[4]; } R, C;
    R.v = qr; C.v = qc;
    float dd = 0.f;
    #pragma unroll
    for (int q = 0; q < 4; q++) {
        unsigned x = R.w[q], y = C.w[q];
        float s0 = (float)(x & 0xffu);
        float s1 = (float)((x >> 8) & 0xffu);
        float s2 = (float)((x >> 16) & 0xffu);
        float s3 = (float)(x >> 24);
        float c0 = (float)(y & 0xffu);
        float c1 = (float)((y >> 8) & 0xffu);
        float c2 = (float)((y >> 16) & 0xffu);
        float c3 = (float)(y >> 24);
        dd = fmaf(s0, c0, dd); dd = fmaf(s1, c1, dd);
        dd = fmaf(s2, c2, dd); dd = fmaf(s3, c3, dd);
        lf[4 * q + 0] = fmaf(a, s0, lf[4 * q + 0]);
        lf[4 * q + 1] = fmaf(a, s1, lf[4 * q + 1]);
        lf[4 * q + 2] = fmaf(a, s2, lf[4 * q + 2]);
        lf[4 * q + 3] = fmaf(a, s3, lf[4 * q + 3]);
    }
    m2l += a;
    trl = fmaf(a, dd, trl);
}

__global__ __launch_bounds__(256) void k_edges_u8(const int* __restrict__ rows,
                                                  const int* __restrict__ cols,
                                                  const float* __restrict__ adj,
                                                  const uint4* __restrict__ Sb4,
                                                  float* __restrict__ m2_g,
                                                  float* __restrict__ tr_g,
                                                  float* __restrict__ left_g) {
    float m2l = 0.f, trl = 0.f;
    float lf[KC];
    #pragma unroll
    for (int k = 0; k < KC; k++) lf[k] = 0.f;

    const int NU = NE / 4;                        // 800K 4-edge units
    const int stride = gridDim.x * blockDim.x;
    for (int u = blockIdx.x * blockDim.x + threadIdx.x; u < NU; u += stride) {
        int4   r4 = *(const int4*)(rows + 4 * (size_t)u);
        int4   c4 = *(const int4*)(cols + 4 * (size_t)u);
        float4 a4 = *(const float4*)(adj + 4 * (size_t)u);
        uint4 qr0 = Sb4[r4.x];                    // 8 independent 16 B gathers
        uint4 qc0 = Sb4[c4.x];
        uint4 qr1 = Sb4[r4.y];
        uint4 qc1 = Sb4[c4.y];
        uint4 qr2 = Sb4[r4.z];
        uint4 qc2 = Sb4[c4.z];
        uint4 qr3 = Sb4[r4.w];
        uint4 qc3 = Sb4[c4.w];
        edge_acc_u8(qr0, qc0, a4.x, lf, m2l, trl);
        edge_acc_u8(qr1, qc1, a4.y, lf, m2l, trl);
        edge_acc_u8(qr2, qc2, a4.z, lf, m2l, trl);
        edge_acc_u8(qr3, qc3, a4.w, lf, m2l, trl);
    }

    trl *= (1.f / 65025.f);
    #pragma unroll
    for (int k = 0; k < KC; k++) lf[k] *= (1.f / 255.f);

    #pragma unroll
    for (int off = 32; off >= 1; off >>= 1) {
        m2l += __shfl_xor(m2l, off);
        trl += __shfl_xor(trl, off);
    }
    #pragma unroll
    for (int k = 0; k < KC; k++) {
        float v = lf[k];
        #pragma unroll
        for (int off = 32; off >= 1; off >>= 1) v += __shfl_xor(v, off);
        lf[k] = v;
    }
    __shared__ float red[4][18];
    int w = threadIdx.x >> 6;
    if ((threadIdx.x & 63) == 0) {
        red[w][0] = m2l; red[w][1] = trl;
        #pragma unroll
        for (int k = 0; k < KC; k++) red[w][2 + k] = lf[k];
    }
    __syncthreads();
    int t = threadIdx.x;
    if (t < 18) {
        float v = red[0][t] + red[1][t] + red[2][t] + red[3][t];
        float* dst = (t == 0) ? m2_g : (t == 1) ? tr_g : &left_g[t - 2];
        atomicAdd(dst, v);
    }
}

// ---------------------------------------------------------------------------
// f32 fallback edge kernel (workspace too small for Sb)
// ---------------------------------------------------------------------------
__global__ __launch_bounds__(256) void k_edges_f32(const int* __restrict__ rows,
                                                   const int* __restrict__ cols,
                                                   const float* __restrict__ adj,
                                                   const float* __restrict__ S,
                                                   float* __restrict__ m2_g,
                                                   float* __restrict__ tr_g,
                                                   float* __restrict__ left_g) {
    float m2l = 0.f, trl = 0.f;
    float lf[KC];
    #pragma unroll
    for (int k = 0; k < KC; k++) lf[k] = 0.f;

    int stride = gridDim.x * blockDim.x;
    for (int e = blockIdx.x * blockDim.x + threadIdx.x; e < NE; e += stride) {
        int r = rows[e], c = cols[e];
        float a = adj[e];
        float sv[KC], cv[KC];
        const float4* sr = (const float4*)(S + (size_t)r * KC);
        const float4* sc = (const float4*)(S + (size_t)c * KC);
        #pragma unroll
        for (int qq = 0; qq < 4; qq++) {
            float4 s4 = sr[qq], c4 = sc[qq];
            sv[4*qq]=s4.x; sv[4*qq+1]=s4.y; sv[4*qq+2]=s4.z; sv[4*qq+3]=s4.w;
            cv[4*qq]=c4.x; cv[4*qq+1]=c4.y; cv[4*qq+2]=c4.z; cv[4*qq+3]=c4.w;
        }
        float dd = 0.f;
        #pragma unroll
        for (int k = 0; k < KC; k++) {
            dd += sv[k] * cv[k];
            lf[k] += a * sv[k];
        }
        m2l += a;
        trl += a * dd;
    }

    #pragma unroll
    for (int off = 32; off >= 1; off >>= 1) {
        m2l += __shfl_xor(m2l, off);
        trl += __shfl_xor(trl, off);
    }
    #pragma unroll
    for (int k = 0; k < KC; k++) {
        float v = lf[k];
        #pragma unroll
        for (int off = 32; off >= 1; off >>= 1) v += __shfl_xor(v, off);
        lf[k] = v;
    }
    __shared__ float red[4][18];
    int w = threadIdx.x >> 6;
    if ((threadIdx.x & 63) == 0) {
        red[w][0] = m2l; red[w][1] = trl;
        #pragma unroll
        for (int k = 0; k < KC; k++) red[w][2 + k] = lf[k];
    }
    __syncthreads();
    int t = threadIdx.x;
    if (t < 18) {
        float v = red[0][t] + red[1][t] + red[2][t] + red[3][t];
        float* dst = (t == 0) ? m2_g : (t == 1) ? tr_g : &left_g[t - 2];
        atomicAdd(dst, v);
    }
}

// ---------------------------------------------------------------------------
// epilogue: features_pooled = selu(stx/cs), spectral & collapse losses (f32)
// ---------------------------------------------------------------------------
__global__ __launch_bounds__(256) void k_final(const float* __restrict__ cs,
                                               const float* __restrict__ left,
                                               const float* __restrict__ m2p,
                                               const float* __restrict__ trp,
                                               const float* __restrict__ stx,
                                               float* __restrict__ out) {
    int t = threadIdx.x;
    #pragma unroll
    for (int k = 0; k < KC; k++) {
        float v = stx[k * DIM + t] / cs[k];
        float r = (v > 0.f) ? 1.0507009873554805f * v
                            : 1.7580993408473766f * (__expf(v) - 1.f);
        out[k * DIM + t] = r;
    }
    if (t == 0) {
        float m2 = *m2p;
        float tn = 0.f;
        #pragma unroll
        for (int k = 0; k < KC; k++) tn += left[k] * left[k];
        tn /= m2;
        float spectral = -((*trp) - tn) / m2;
        float ss = 0.f;
        #pragma unroll
        for (int k = 0; k < KC; k++) ss += cs[k] * cs[k];
        float collapse = 0.1f * (sqrtf(ss) / (float)N_NODES * 4.0f - 1.0f);
        out[KC * DIM + (size_t)N_NODES * KC]     = spectral;
        out[KC * DIM + (size_t)N_NODES * KC + 1] = collapse;
    }
}

extern "C" void kernel_launch(void* const* d_in, const int* in_sizes, int n_in,
                              void* d_out, int out_size, void* d_ws, size_t ws_size,
                              hipStream_t stream) {
    (void)out_size;

    const float* X    = nullptr;
    const int*   ei   = nullptr;
    const float* adj  = nullptr;
    const float* W    = nullptr;
    const float* bias = nullptr;
    for (int i = 0; i < n_in; i++) {
        switch (in_sizes[i]) {
            case 25600000: X    = (const float*)d_in[i]; break;
            case  6400000: ei   = (const int*)d_in[i];   break;
            case  3200000: adj  = (const float*)d_in[i]; break;
            case     4096: W    = (const float*)d_in[i]; break;
            case       16: bias = (const float*)d_in[i]; break;
        }
    }

    float* out = (float*)d_out;
    float* S   = out + KC * DIM;    // assignments [100000,16] f32
    const int* rows = ei;
    const int* cols = ei + NE;

    float* ws   = (float*)d_ws;
    float* cs   = ws;
    float* left = ws + 16;
    float* m2   = ws + 32;
    float* tr   = ws + 33;
    float* stx  = ws + 64;
    unsigned* Sb = (unsigned*)(ws + 64 + KC * DIM);   // u8-packed S, 16 B/node
    const size_t need = (64 + KC * DIM) * sizeof(float) + (size_t)N_NODES * 16;
    const bool use_pack = (ws_size >= need);   // fixed per process -> graph-safe

    hipMemsetAsync(d_ws, 0, (64 + KC * DIM) * sizeof(float), stream);

    if (use_pack) {
        k_assign_stx<true><<<NCHUNKS, 256, 0, stream>>>(
            (const float4*)X, (const float4*)W, bias, S, Sb, cs, stx);
        k_edges_u8<<<2048, 256, 0, stream>>>(rows, cols, adj, (const uint4*)Sb,
                                             m2, tr, left);
    } else {
        k_assign_stx<false><<<NCHUNKS, 256, 0, stream>>>(
            (const float4*)X, (const float4*)W, bias, S, Sb, cs, stx);
        k_edges_f32<<<2048, 256, 0, stream>>>(rows, cols, adj, S, m2, tr, left);
    }
    k_final<<<1, 256, 0, stream>>>(cs, left, m2, tr, stx, out);
}